// Round 9
// baseline (219.958 us; speedup 1.0000x reference)
//
#include <hip/hip_runtime.h>
#include <hip/hip_bf16.h>
#include <hip/hip_cooperative_groups.h>

namespace cg = cooperative_groups;

// B=4, C=256, N=HW=4096, Dqk=32.
// Round 9: the ~80us outside attn has been INVARIANT across six qkv rewrites ->
// fixed per-launch overhead / inter-kernel bubbles, not kernel internals. Fuse
// everything into ONE cooperative kernel (256 blocks x 1024 thr, 1 block/CU,
// co-resident): [wpack (blocks 0..9) || x-stage] -> grid.sync -> qkv (64-pixel
// tiles) -> grid.sync -> attn (R8 structure, verified 65us, + unroll 2 to kill
// register-rotation movs). LDS phases alias one 36.9KB buffer.
// Carried: packed-W A-frags (LOG2E in Wq), packed-V B-frag layout (R8's 2.2x win:
// coalesced 1KB V loads), S^T trick, no-max softmax, LDS-only barrier, XCD swizzle.

#define N_PIX 4096
#define DQK   32
#define CCH   256
#define LOG2E 1.44269504088896f

typedef __attribute__((ext_vector_type(8))) _Float16 f16x8;
typedef __attribute__((ext_vector_type(4))) _Float16 f16x4;
typedef __attribute__((ext_vector_type(2))) _Float16 f16x2;
typedef __attribute__((ext_vector_type(8))) short    bf16x8;
typedef __attribute__((ext_vector_type(4))) short    bf16x4;
typedef __attribute__((ext_vector_type(4))) float    f32x4;

__device__ inline void barrier_lds() {
    asm volatile("" ::: "memory");
    __builtin_amdgcn_s_waitcnt(0xc07f);   // vmcnt=63, expcnt=7, lgkmcnt=0
    __builtin_amdgcn_s_barrier();
    asm volatile("" ::: "memory");
}

__device__ inline short bf16bits(float f) {
    __hip_bfloat16 h = __float2bfloat16(f);
    return *(short*)&h;
}

__global__ __launch_bounds__(1024, 1) void fused_kernel(
    const float* __restrict__ x,
    const float* __restrict__ Wq, const float* __restrict__ bq,
    const float* __restrict__ Wk, const float* __restrict__ bk,
    const float* __restrict__ Wv, const float* __restrict__ bv,
    _Float16* __restrict__ qo, _Float16* __restrict__ ko,
    __hip_bfloat16* __restrict__ vp,   // packed V: [B][2048 chunks][64][8]
    _Float16* __restrict__ Wp,         // packed W: [160 chunks][64][8]
    float* __restrict__ out)           // [B][C][N]
{
    __shared__ alignas(16) unsigned char shraw[36864];
    _Float16       (*xT)[264]     = (_Float16 (*)[264])shraw;
    __hip_bfloat16 (*vst)[72]     = (__hip_bfloat16 (*)[72])shraw;
    __hip_bfloat16 (*Ps)[64][72]  = (__hip_bfloat16 (*)[64][72])shraw;
    float          (*lsum)[4][16] = (float (*)[4][16])(shraw + 2 * 64 * 72 * 2);

    const int idx  = blockIdx.x;
    const int tid  = threadIdx.x;
    const int wid  = tid >> 6;
    const int lane = tid & 63;
    const int L15  = lane & 15;
    const int quad = lane >> 4;

    const int b  = (idx & 7) >> 1;                   // batch -> XCD pair
    const int nt = ((idx >> 3) << 1) | (idx & 1);    // 0..63 tile within batch
    const int n0 = nt * 64;

    const f32x4 fz = {0.f, 0.f, 0.f, 0.f};

    // ================= phase 0: stage x tile (all blocks) ====================
    {
        const float* xb = x + (size_t)b * CCH * N_PIX;
        float4 ld[2][2];
        int c2s[2], n4s[2];
        #pragma unroll
        for (int pass = 0; pass < 2; ++pass) {
            const int flat = pass * 1024 + tid;
            c2s[pass] = (flat >> 4) * 2;
            n4s[pass] = (flat & 15) * 4;
            ld[pass][0] = *(const float4*)(xb + (size_t)c2s[pass]       * N_PIX + n0 + n4s[pass]);
            ld[pass][1] = *(const float4*)(xb + (size_t)(c2s[pass] + 1) * N_PIX + n0 + n4s[pass]);
        }
        #pragma unroll
        for (int pass = 0; pass < 2; ++pass) {
            const float a[4] = {ld[pass][0].x, ld[pass][0].y, ld[pass][0].z, ld[pass][0].w};
            const float c[4] = {ld[pass][1].x, ld[pass][1].y, ld[pass][1].z, ld[pass][1].w};
            #pragma unroll
            for (int i = 0; i < 4; ++i)
                *(f16x2*)(&xT[n4s[pass] + i][c2s[pass]]) =
                    (f16x2){(_Float16)a[i], (_Float16)c[i]};
        }
    }

    // ============ phase 0b: W pack (blocks 0..9, 16 chunks each) =============
    if (idx < 10) {
        const int wflat = idx * 16 + wid;   // 0..159
        const int mt    = wflat >> 3;
        const int ks    = wflat & 7;
        const int m0    = mt * 16;
        const float* Wsrc; int row; float scale = 1.f;
        if (m0 < 32)      { Wsrc = Wq; row = m0 + L15;      scale = LOG2E; }
        else if (m0 < 64) { Wsrc = Wk; row = m0 - 32 + L15; }
        else              { Wsrc = Wv; row = m0 - 64 + L15; }
        const float* p = Wsrc + (size_t)row * 256 + ks * 32 + quad * 8;
        f16x8 h;
        #pragma unroll
        for (int j = 0; j < 8; ++j) h[j] = (_Float16)(p[j] * scale);
        *(f16x8*)(Wp + ((size_t)wflat * 64 + lane) * 8) = h;
    }

    cg::this_grid().sync();

    // ================= phase 1: QKV projection (f16 MFMA) ====================
    {
        const int nf  = wid & 3;
        const int mtg = wid >> 2;

        f32x4 acc[5];
        #pragma unroll
        for (int mt = 0; mt < 5; ++mt) acc[mt] = fz;

        const _Float16* wpw = Wp + ((size_t)(mtg * 5) * 8 * 64 + lane) * 8;

        #pragma unroll
        for (int ks = 0; ks < 8; ++ks) {
            const f16x8 bfr = *(const f16x8*)(&xT[nf * 16 + L15][ks * 32 + quad * 8]);
            #pragma unroll
            for (int mt = 0; mt < 5; ++mt) {
                const f16x8 afr = *(const f16x8*)(wpw + (size_t)(mt * 8 + ks) * 512);
                acc[mt] = __builtin_amdgcn_mfma_f32_16x16x32_f16(afr, bfr, acc[mt], 0, 0, 0);
            }
        }

        const int np = nf * 16 + L15;
        const int n  = n0 + np;
        #pragma unroll
        for (int mt = 0; mt < 5; ++mt) {
            const int m0 = (mtg * 5 + mt) * 16;
            const f32x4 a = acc[mt];
            if (m0 < 32) {
                const int mr = m0 + quad * 4;
                f16x4 h;
                #pragma unroll
                for (int r = 0; r < 4; ++r) h[r] = (_Float16)(a[r] + bq[mr + r] * LOG2E);
                *(f16x4*)(qo + ((size_t)b * N_PIX + n) * DQK + mr) = h;
            } else if (m0 < 64) {
                const int mr = m0 - 32 + quad * 4;
                f16x4 h;
                #pragma unroll
                for (int r = 0; r < 4; ++r) h[r] = (_Float16)(a[r] + bk[mr + r]);
                *(f16x4*)(ko + ((size_t)b * N_PIX + n) * DQK + mr) = h;
            }
        }

        __syncthreads();   // xT dead -> vst aliases it

        #pragma unroll
        for (int mt = 0; mt < 5; ++mt) {
            const int m0 = (mtg * 5 + mt) * 16;
            if (m0 >= 64) {
                const int c = m0 - 64 + quad * 4;
                #pragma unroll
                for (int r = 0; r < 4; ++r)
                    vst[c + r][np] = __float2bfloat16(acc[mt][r] + bv[c + r]);
            }
        }
        __syncthreads();

        __hip_bfloat16* vpb0 = vp + (size_t)b * 2048 * 512 + (size_t)(nt * 2) * 16 * 512;
        #pragma unroll
        for (int s = 0; s < 2; ++s) {
            const int slot = s * 1024 + tid;
            const int nch  = slot >> 10;
            const int rem  = slot & 1023;
            const int cg16 = rem >> 6;
            const int ln   = rem & 63;
            const bf16x8 val = *(const bf16x8*)(&vst[cg16 * 16 + (ln & 15)][nch * 32 + (ln >> 4) * 8]);
            *(bf16x8*)(vpb0 + ((size_t)(nch * 16 + cg16) * 64 + ln) * 8) = val;
        }
    }

    cg::this_grid().sync();

    // ================= phase 2: attention ====================================
    {
        const int qt = wid & 3;
        const int kt = wid >> 2;
        const int qp = wid & 1;
        const int cg = wid >> 1;
        const int c0 = cg * 32;

        const f16x8 aq = *(const f16x8*)(qo + ((size_t)b * N_PIX + n0 + qt * 16 + L15) * DQK + quad * 8);

        f32x4 oacc[2][2];
        #pragma unroll
        for (int qq = 0; qq < 2; ++qq)
            #pragma unroll
            for (int cf = 0; cf < 2; ++cf) oacc[qq][cf] = fz;
        float psum = 0.f;

        const _Float16* kptr =
            ko + (size_t)b * N_PIX * DQK + (size_t)(kt * 16 + L15) * DQK + quad * 8;
        const __hip_bfloat16* vpb = vp + (size_t)b * 2048 * 512 + (size_t)lane * 8;

        const f16x8 k0f = *(const f16x8*)kptr;
        f16x8 kcur = *(const f16x8*)(kptr + 64 * DQK);
        bf16x8 vcur[2][2], vnext[2][2];
        #pragma unroll
        for (int kk = 0; kk < 2; ++kk)
            #pragma unroll
            for (int cf = 0; cf < 2; ++cf) {
                vcur[kk][cf]  = *(const bf16x8*)(vpb + (size_t)(kk * 16       + cg * 2 + cf) * 512);
                vnext[kk][cf] = *(const bf16x8*)(vpb + (size_t)((2 + kk) * 16 + cg * 2 + cf) * 512);
            }
        {
            const f32x4 s = __builtin_amdgcn_mfma_f32_16x16x32_f16(k0f, aq, fz, 0, 0, 0);
            bf16x4 pk;
            #pragma unroll
            for (int r = 0; r < 4; ++r) { const float p = exp2f(s[r]); psum += p; pk[r] = bf16bits(p); }
            *(bf16x4*)(&Ps[0][qt * 16 + L15][kt * 16 + quad * 4]) = pk;
        }
        barrier_lds();

        #pragma unroll 2
        for (int it = 0; it < 64; ++it) {
            const int buf = it & 1;
            const int ld  = (it + 2 < 64) ? it + 2 : 63;

            const f16x8 knew = *(const f16x8*)(kptr + (size_t)ld * 64 * DQK);
            bf16x8 vnew[2][2];
            #pragma unroll
            for (int kk = 0; kk < 2; ++kk)
                #pragma unroll
                for (int cf = 0; cf < 2; ++cf)
                    vnew[kk][cf] = *(const bf16x8*)(vpb + (size_t)((ld * 2 + kk) * 16 + cg * 2 + cf) * 512);

            #pragma unroll
            for (int qq = 0; qq < 2; ++qq)
                #pragma unroll
                for (int kk = 0; kk < 2; ++kk) {
                    const bf16x8 ap = *(const bf16x8*)(&Ps[buf][(qp * 2 + qq) * 16 + L15][kk * 32 + quad * 8]);
                    #pragma unroll
                    for (int cf = 0; cf < 2; ++cf)
                        oacc[qq][cf] = __builtin_amdgcn_mfma_f32_16x16x32_bf16(ap, vcur[kk][cf], oacc[qq][cf], 0, 0, 0);
                }

            if (it < 63) {
                const f32x4 s = __builtin_amdgcn_mfma_f32_16x16x32_f16(kcur, aq, fz, 0, 0, 0);
                bf16x4 pk;
                #pragma unroll
                for (int r = 0; r < 4; ++r) { const float p = exp2f(s[r]); psum += p; pk[r] = bf16bits(p); }
                *(bf16x4*)(&Ps[buf ^ 1][qt * 16 + L15][kt * 16 + quad * 4]) = pk;
            }
            barrier_lds();

            kcur = knew;
            #pragma unroll
            for (int kk = 0; kk < 2; ++kk)
                #pragma unroll
                for (int cf = 0; cf < 2; ++cf) {
                    vcur[kk][cf]  = vnext[kk][cf];
                    vnext[kk][cf] = vnew[kk][cf];
                }
        }

        psum += __shfl_xor(psum, 16, 64);
        psum += __shfl_xor(psum, 32, 64);
        if (quad == 0) lsum[qt][kt][L15] = psum;
        __syncthreads();

        float* ob = out + (size_t)b * CCH * N_PIX;
        #pragma unroll
        for (int qq = 0; qq < 2; ++qq) {
            const int qtile = qp * 2 + qq;
            float inv_l[4];
            #pragma unroll
            for (int r = 0; r < 4; ++r) {
                const int q = quad * 4 + r;
                inv_l[r] = 1.f / (lsum[qtile][0][q] + lsum[qtile][1][q] +
                                  lsum[qtile][2][q] + lsum[qtile][3][q]);
            }
            #pragma unroll
            for (int cf = 0; cf < 2; ++cf) {
                const int c = c0 + cf * 16 + L15;
                f32x4 o;
                #pragma unroll
                for (int r = 0; r < 4; ++r) o[r] = oacc[qq][cf][r] * inv_l[r];
                *(f32x4*)(ob + (size_t)c * N_PIX + n0 + qtile * 16 + quad * 4) = o;
            }
        }
    }
}

// ---------------------------------------------------------------------------
extern "C" void kernel_launch(void* const* d_in, const int* in_sizes, int n_in,
                              void* d_out, int out_size, void* d_ws, size_t ws_size,
                              hipStream_t stream) {
    (void)in_sizes; (void)n_in; (void)out_size; (void)ws_size;
    const float* x  = (const float*)d_in[0];
    const float* Wq = (const float*)d_in[1];
    const float* bq = (const float*)d_in[2];
    const float* Wk = (const float*)d_in[3];
    const float* bk = (const float*)d_in[4];
    const float* Wv = (const float*)d_in[5];
    const float* bv = (const float*)d_in[6];

    // workspace: q 1MB | k 1MB | Vp 8MB | Wp 160KB
    _Float16* qb = (_Float16*)d_ws;
    _Float16* kb = qb + (size_t)4 * N_PIX * DQK;
    __hip_bfloat16* vpk = (__hip_bfloat16*)(kb + (size_t)4 * N_PIX * DQK);
    _Float16* wp = (_Float16*)(vpk + (size_t)4 * 2048 * 512);
    float* outp = (float*)d_out;

    void* args[] = { (void*)&x, (void*)&Wq, (void*)&bq, (void*)&Wk, (void*)&bk,
                     (void*)&Wv, (void*)&bv, (void*)&qb, (void*)&kb, (void*)&vpk,
                     (void*)&wp, (void*)&outp };
    hipLaunchCooperativeKernel((const void*)fused_kernel, dim3(256), dim3(1024),
                               args, 0, stream);
}

// Round 10
// 153.417 us; speedup vs baseline: 1.4337x; 1.4337x over previous
//
#include <hip/hip_runtime.h>
#include <hip/hip_bf16.h>

// B=4, C=256, N=HW=4096, Dqk=32.
// Round 10: R9 showed ~85us of the bench total is HARNESS overhead outside dispatches
// (fused dispatch 134.7 vs total 220; R8 dispatch sum ~72 vs total 147). qkv was ~5us
// all along. Revert to R8's 3-kernel split (attn 65.2us verified) and attack attn's
// barrier-convoy: 2446 cyc/64-key iter vs ~500-cyc pipe floors = lockstep overhead.
//  - 128-key super-iters: Ps = 2 x [64q][128k(+pad)] -> 32 barriers, not 64.
//  - parity prefetch buffers (vb[SI&1], kc[(SI+1)&1], reload after last use):
//    distance ~1.7 super-iter, zero rotation movs.
// Carried: packed-V B-frag layout (R8 2.2x win), packed-W, S^T trick, no-max softmax
// (exp2, LOG2E in Wq), LDS-only barrier, XCD batch swizzle.

#define N_PIX 4096
#define DQK   32
#define CCH   256
#define LOG2E 1.44269504088896f

typedef __attribute__((ext_vector_type(8))) _Float16 f16x8;
typedef __attribute__((ext_vector_type(4))) _Float16 f16x4;
typedef __attribute__((ext_vector_type(2))) _Float16 f16x2;
typedef __attribute__((ext_vector_type(8))) short    bf16x8;
typedef __attribute__((ext_vector_type(4))) short    bf16x4;
typedef __attribute__((ext_vector_type(4))) float    f32x4;

// LDS-only block barrier: waits lgkmcnt(0) but leaves vmcnt untouched.
__device__ inline void barrier_lds() {
    asm volatile("" ::: "memory");
    __builtin_amdgcn_s_waitcnt(0xc07f);   // vmcnt=63, expcnt=7, lgkmcnt=0
    __builtin_amdgcn_s_barrier();
    asm volatile("" ::: "memory");
}

__device__ inline short bf16bits(float f) {
    __hip_bfloat16 h = __float2bfloat16(f);
    return *(short*)&h;
}

// ---------------------------------------------------------------------------
// Kernel 0: pack Wq|Wk|Wv -> f16 A-fragments, lane-ordered (LOG2E folded into Wq).
// ---------------------------------------------------------------------------
__global__ __launch_bounds__(256) void wpack_kernel(
    const float* __restrict__ Wq, const float* __restrict__ Wk,
    const float* __restrict__ Wv, _Float16* __restrict__ Wp)
{
    const int tid   = threadIdx.x;
    const int wflat = blockIdx.x * 4 + (tid >> 6);   // 0..159
    const int lane  = tid & 63;
    const int L15   = lane & 15;
    const int quad  = lane >> 4;
    const int mt    = wflat >> 3;
    const int ks    = wflat & 7;
    const int m0    = mt * 16;

    const float* Wsrc; int row; float scale = 1.f;
    if (m0 < 32)      { Wsrc = Wq; row = m0 + L15;      scale = LOG2E; }
    else if (m0 < 64) { Wsrc = Wk; row = m0 - 32 + L15; }
    else              { Wsrc = Wv; row = m0 - 64 + L15; }

    const float* p = Wsrc + (size_t)row * 256 + ks * 32 + quad * 8;
    f16x8 h;
    #pragma unroll
    for (int j = 0; j < 8; ++j) h[j] = (_Float16)(p[j] * scale);
    *(f16x8*)(Wp + ((size_t)wflat * 64 + lane) * 8) = h;
}

// ---------------------------------------------------------------------------
// Kernel 1: QKV projection, f16 MFMA, packed W (R8 version, ~5us). Grid 512,
// 512 thr = 8 waves, 32-pixel tiles. V goes through LDS -> packed B-frag layout.
// ---------------------------------------------------------------------------
__global__ __launch_bounds__(512, 4) void qkv_kernel(
    const float* __restrict__ x, const _Float16* __restrict__ Wp,
    const float* __restrict__ bq, const float* __restrict__ bk,
    const float* __restrict__ bv,
    _Float16* __restrict__ qo, _Float16* __restrict__ ko,
    __hip_bfloat16* __restrict__ vp)
{
    __shared__ alignas(16) unsigned char shraw[256 * 40 * 2];
    _Float16       (*xT)[264] = (_Float16 (*)[264])shraw;
    __hip_bfloat16 (*vst)[40] = (__hip_bfloat16 (*)[40])shraw;

    const int idx = blockIdx.x;
    const int b   = (idx & 7) >> 1;
    const int n0  = (((idx >> 3) << 1) | (idx & 1)) * 32;
    const int tid = threadIdx.x;

    {
        const float* xb = x + (size_t)b * CCH * N_PIX;
        float4 ld[2][2];
        int c2s[2], n4s[2];
        #pragma unroll
        for (int pass = 0; pass < 2; ++pass) {
            const int flat = pass * 512 + tid;
            c2s[pass] = (flat >> 3) * 2;
            n4s[pass] = (flat & 7) * 4;
            ld[pass][0] = *(const float4*)(xb + (size_t)c2s[pass]       * N_PIX + n0 + n4s[pass]);
            ld[pass][1] = *(const float4*)(xb + (size_t)(c2s[pass] + 1) * N_PIX + n0 + n4s[pass]);
        }
        #pragma unroll
        for (int pass = 0; pass < 2; ++pass) {
            const float a[4] = {ld[pass][0].x, ld[pass][0].y, ld[pass][0].z, ld[pass][0].w};
            const float c[4] = {ld[pass][1].x, ld[pass][1].y, ld[pass][1].z, ld[pass][1].w};
            #pragma unroll
            for (int i = 0; i < 4; ++i)
                *(f16x2*)(&xT[n4s[pass] + i][c2s[pass]]) =
                    (f16x2){(_Float16)a[i], (_Float16)c[i]};
        }
    }
    __syncthreads();

    const int lane = tid & 63;
    const int wid  = tid >> 6;
    const int L15  = lane & 15;
    const int quad = lane >> 4;
    const int nf   = wid & 1;
    const int mtg  = wid >> 1;

    const f32x4 fz = {0.f, 0.f, 0.f, 0.f};
    f32x4 acc[5];
    #pragma unroll
    for (int mt = 0; mt < 5; ++mt) acc[mt] = fz;

    const _Float16* wpw = Wp + ((size_t)(mtg * 5) * 8 * 64 + lane) * 8;

    #pragma unroll
    for (int ks = 0; ks < 8; ++ks) {
        const f16x8 bfr = *(const f16x8*)(&xT[nf * 16 + L15][ks * 32 + quad * 8]);
        #pragma unroll
        for (int mt = 0; mt < 5; ++mt) {
            const f16x8 afr = *(const f16x8*)(wpw + (size_t)(mt * 8 + ks) * 512);
            acc[mt] = __builtin_amdgcn_mfma_f32_16x16x32_f16(afr, bfr, acc[mt], 0, 0, 0);
        }
    }

    const int np = nf * 16 + L15;
    const int n  = n0 + np;
    #pragma unroll
    for (int mt = 0; mt < 5; ++mt) {
        const int m0 = (mtg * 5 + mt) * 16;
        const f32x4 a = acc[mt];
        if (m0 < 32) {
            const int mr = m0 + quad * 4;
            f16x4 h;
            #pragma unroll
            for (int r = 0; r < 4; ++r) h[r] = (_Float16)(a[r] + bq[mr + r] * LOG2E);
            *(f16x4*)(qo + ((size_t)b * N_PIX + n) * DQK + mr) = h;
        } else if (m0 < 64) {
            const int mr = m0 - 32 + quad * 4;
            f16x4 h;
            #pragma unroll
            for (int r = 0; r < 4; ++r) h[r] = (_Float16)(a[r] + bk[mr + r]);
            *(f16x4*)(ko + ((size_t)b * N_PIX + n) * DQK + mr) = h;
        }
    }

    __syncthreads();   // xT dead; vst aliases it

    #pragma unroll
    for (int mt = 0; mt < 5; ++mt) {
        const int m0 = (mtg * 5 + mt) * 16;
        if (m0 >= 64) {
            const int c = m0 - 64 + quad * 4;
            #pragma unroll
            for (int r = 0; r < 4; ++r)
                vst[c + r][np] = __float2bfloat16(acc[mt][r] + bv[c + r]);
        }
    }
    __syncthreads();

    {
        __hip_bfloat16* vpb = vp + (size_t)b * 2048 * 512 + (size_t)((n0 >> 5) * 16) * 512;
        #pragma unroll
        for (int s = 0; s < 2; ++s) {
            const int slot = s * 512 + tid;
            const int cg16 = slot >> 6;
            const int ln   = slot & 63;
            const bf16x8 val = *(const bf16x8*)(&vst[cg16 * 16 + (ln & 15)][(ln >> 4) * 8]);
            *(bf16x8*)(vpb + ((size_t)cg16 * 64 + ln) * 8) = val;
        }
    }
}

// ---------------------------------------------------------------------------
// Kernel 2: attention, 128-key super-iterations. Grid 256, 1024 thr = 16 waves.
// S duty:  wave (qt=wid&3, kt=wid>>2): 2 S^T MFMAs per SI (key slices kt, kt+4);
//          one ds_write_b64 each. PV duty: wave (qp=wid&1, cg=wid>>1): 16 MFMA/SI,
//          8 LDS A-frag b128 reads, 8 coalesced V frags (parity prefetch).
// ---------------------------------------------------------------------------
__global__ __launch_bounds__(1024, 1) void attn_kernel(
    const _Float16* __restrict__ qg,        // [B][N][32], q pre-scaled by log2e
    const _Float16* __restrict__ kg,        // [B][N][32]
    const __hip_bfloat16* __restrict__ vp,  // packed: [B][2048 chunks][64][8]
    float* __restrict__ out)                // [B][C][N]
{
    __shared__ alignas(16) __hip_bfloat16 Ps[2][64][136];  // 34.8KB, rows 272B
    __shared__ float lsum[4][4][16];                       // [qt][kt][query]

    const int idx  = blockIdx.x;
    const int b    = (idx & 7) >> 1;
    const int n0   = (((idx >> 3) << 1) | (idx & 1)) * 64;
    const int tid  = threadIdx.x;
    const int wid  = tid >> 6;
    const int lane = tid & 63;
    const int L15  = lane & 15;
    const int quad = lane >> 4;
    const int qt   = wid & 3;    // S duty: q-tile
    const int kt   = wid >> 2;   // S duty: key-slice pair {kt, kt+4}
    const int qp   = wid & 1;    // PV duty: q-pair {2qp, 2qp+1}
    const int cg   = wid >> 1;   // PV duty: 32-channel group
    const int c0   = cg * 32;

    const f32x4 fz = {0.f, 0.f, 0.f, 0.f};

    const f16x8 aq = *(const f16x8*)(qg + ((size_t)b * N_PIX + n0 + qt * 16 + L15) * DQK + quad * 8);

    f32x4 oacc[2][2];
    #pragma unroll
    for (int qq = 0; qq < 2; ++qq)
        #pragma unroll
        for (int cf = 0; cf < 2; ++cf) oacc[qq][cf] = fz;
    float psum = 0.f;

    // K base for this wave's slices: row = SI*128 + h*64 + kt*16 + L15
    const _Float16* kbase =
        kg + (size_t)b * N_PIX * DQK + (size_t)(kt * 16 + L15) * DQK + quad * 8;
    const __hip_bfloat16* vpb = vp + (size_t)b * 2048 * 512 + (size_t)lane * 8;

    // ---- prologue: S(0) direct; kc parity slots = K(1), K(2); vb parity = V(0), V(1)
    f16x8 kc[2][2];   // [parity of consuming SI+1][h]
    bf16x8 vb[2][4][2];   // [parity of SI][kk][cf]
    {
        #pragma unroll
        for (int h = 0; h < 2; ++h) {
            const f16x8 k0 = *(const f16x8*)(kbase + (size_t)(h * 64) * DQK);
            const f32x4 s  = __builtin_amdgcn_mfma_f32_16x16x32_f16(k0, aq, fz, 0, 0, 0);
            bf16x4 pk;
            #pragma unroll
            for (int r = 0; r < 4; ++r) { const float p = exp2f(s[r]); psum += p; pk[r] = bf16bits(p); }
            *(bf16x4*)(&Ps[0][qt * 16 + L15][(kt + 4 * h) * 16 + quad * 4]) = pk;
        }
        #pragma unroll
        for (int h = 0; h < 2; ++h) {
            kc[1][h] = *(const f16x8*)(kbase + (size_t)(128 + h * 64) * DQK);   // K(1)
            kc[0][h] = *(const f16x8*)(kbase + (size_t)(256 + h * 64) * DQK);   // K(2)
        }
        #pragma unroll
        for (int p2 = 0; p2 < 2; ++p2)
            #pragma unroll
            for (int kk = 0; kk < 4; ++kk)
                #pragma unroll
                for (int cf = 0; cf < 2; ++cf)
                    vb[p2][kk][cf] = *(const bf16x8*)(vpb + (size_t)((p2 * 4 + kk) * 16 + cg * 2 + cf) * 512);
    }
    barrier_lds();

    #pragma unroll 2
    for (int SI = 0; SI < 32; ++SI) {
        const int p = SI & 1;

        // ---- PV(SI): 16 MFMA over 128 keys x 32 channels x q-pair
        #pragma unroll
        for (int kk = 0; kk < 4; ++kk)
            #pragma unroll
            for (int qq = 0; qq < 2; ++qq) {
                const bf16x8 ap = *(const bf16x8*)(&Ps[p][(qp * 2 + qq) * 16 + L15][kk * 32 + quad * 8]);
                #pragma unroll
                for (int cf = 0; cf < 2; ++cf)
                    oacc[qq][cf] = __builtin_amdgcn_mfma_f32_16x16x32_bf16(ap, vb[p][kk][cf], oacc[qq][cf], 0, 0, 0);
            }

        // ---- S(SI+1): 2 MFMAs, consumes kc[p^1]
        if (SI < 31) {
            #pragma unroll
            for (int h = 0; h < 2; ++h) {
                const f32x4 s = __builtin_amdgcn_mfma_f32_16x16x32_f16(kc[p ^ 1][h], aq, fz, 0, 0, 0);
                bf16x4 pk;
                #pragma unroll
                for (int r = 0; r < 4; ++r) { const float pv = exp2f(s[r]); psum += pv; pk[r] = bf16bits(pv); }
                *(bf16x4*)(&Ps[p ^ 1][qt * 16 + L15][(kt + 4 * h) * 16 + quad * 4]) = pk;
            }
        }

        // ---- parity prefetch (slots just consumed): K(SI+3) -> kc[p^1], V(SI+2) -> vb[p]
        {
            const int ksi = (SI + 3 < 32) ? SI + 3 : 31;
            #pragma unroll
            for (int h = 0; h < 2; ++h)
                kc[p ^ 1][h] = *(const f16x8*)(kbase + ((size_t)ksi * 128 + h * 64) * DQK);
            const int vsi = (SI + 2 < 32) ? SI + 2 : 31;
            #pragma unroll
            for (int kk = 0; kk < 4; ++kk)
                #pragma unroll
                for (int cf = 0; cf < 2; ++cf)
                    vb[p][kk][cf] = *(const bf16x8*)(vpb + (size_t)((vsi * 4 + kk) * 16 + cg * 2 + cf) * 512);
        }
        barrier_lds();   // LDS-only: vmcnt prefetches stay in flight
    }

    // ---- row-sums: reduce over quads (same query), combine kt slices via LDS
    psum += __shfl_xor(psum, 16, 64);
    psum += __shfl_xor(psum, 32, 64);
    if (quad == 0) lsum[qt][kt][L15] = psum;
    __syncthreads();

    float* ob = out + (size_t)b * CCH * N_PIX;
    #pragma unroll
    for (int qq = 0; qq < 2; ++qq) {
        const int qtile = qp * 2 + qq;
        float inv_l[4];
        #pragma unroll
        for (int r = 0; r < 4; ++r) {
            const int q = quad * 4 + r;
            inv_l[r] = 1.f / (lsum[qtile][0][q] + lsum[qtile][1][q] +
                              lsum[qtile][2][q] + lsum[qtile][3][q]);
        }
        #pragma unroll
        for (int cf = 0; cf < 2; ++cf) {
            const int c = c0 + cf * 16 + L15;
            f32x4 o;
            #pragma unroll
            for (int r = 0; r < 4; ++r) o[r] = oacc[qq][cf][r] * inv_l[r];
            *(f32x4*)(ob + (size_t)c * N_PIX + n0 + qtile * 16 + quad * 4) = o;
        }
    }
}

// ---------------------------------------------------------------------------
extern "C" void kernel_launch(void* const* d_in, const int* in_sizes, int n_in,
                              void* d_out, int out_size, void* d_ws, size_t ws_size,
                              hipStream_t stream) {
    (void)in_sizes; (void)n_in; (void)out_size; (void)ws_size;
    const float* x  = (const float*)d_in[0];
    const float* Wq = (const float*)d_in[1];
    const float* bq = (const float*)d_in[2];
    const float* Wk = (const float*)d_in[3];
    const float* bk = (const float*)d_in[4];
    const float* Wv = (const float*)d_in[5];
    const float* bv = (const float*)d_in[6];

    // workspace: q 1MB | k 1MB | Vp 8MB | Wp 160KB
    _Float16* qb = (_Float16*)d_ws;
    _Float16* kb = qb + (size_t)4 * N_PIX * DQK;
    __hip_bfloat16* vpk = (__hip_bfloat16*)(kb + (size_t)4 * N_PIX * DQK);
    _Float16* wp = (_Float16*)(vpk + (size_t)4 * 2048 * 512);
    float* outp = (float*)d_out;

    wpack_kernel<<<40, 256, 0, stream>>>(Wq, Wk, Wv, wp);
    qkv_kernel<<<512, 512, 0, stream>>>(x, wp, bq, bk, bv, qb, kb, vpk);
    attn_kernel<<<256, 1024, 0, stream>>>(qb, kb, vpk, outp);
}